// Round 11
// baseline (2117.689 us; speedup 1.0000x reference)
//
#include <hip/hip_runtime.h>
#include <stdint.h>

#define Bq    2048
#define NNq   24
#define NCq   8
#define CARDq 16
#define Dq    512
#define Hq    8
#define Lq    3
#define FHq   1024
#define Sq    33

typedef unsigned short u16;
typedef unsigned int   u32;
typedef __bf16 bf16x8 __attribute__((ext_vector_type(8)));
typedef float  f32x4  __attribute__((ext_vector_type(4)));

__device__ __forceinline__ u16 f2bf(float f) {   // native v_cvt (RNE)
  return __builtin_bit_cast(u16, (__bf16)f);
}
__device__ __forceinline__ float bf2f(u16 h) {
  u32 u = ((u32)h) << 16;
  return __builtin_bit_cast(float, u);
}

__device__ __forceinline__ void glds16(const void* g, void* l) {
  __builtin_amdgcn_global_load_lds((const __attribute__((address_space(1))) void*)g,
                                   (__attribute__((address_space(3))) void*)l, 16, 0, 0);
}

// ---------------- ALL weight transposes + f32->bf16 in ONE dispatch
__global__ __launch_bounds__(256) void wconv_all_kernel(const float* __restrict__ Wq,
                                                        const float* __restrict__ Wk,
                                                        const float* __restrict__ Wv,
                                                        const float* __restrict__ Wo,
                                                        const float* __restrict__ Wf1,
                                                        const float* __restrict__ Wf2,
                                                        u16* __restrict__ WqkvT,
                                                        u16* __restrict__ WoT,
                                                        u16* __restrict__ Wf1T,
                                                        u16* __restrict__ Wf2T) {
  __shared__ float tile[32][33];
  const int l = blockIdx.y;
  int id = blockIdx.x;
  const float* src; u16* dst; int K, N;
  if (id < 768) {
    const int m = id >> 8; id &= 255;
    src = ((m == 0) ? Wq : (m == 1) ? Wk : Wv) + (size_t)l * 262144;
    dst = WqkvT + (size_t)l * 786432 + (size_t)m * 262144;
    K = 512; N = 512;
  } else if (id < 1024) {
    id -= 768;
    src = Wo + (size_t)l * 262144;  dst = WoT + (size_t)l * 262144;
    K = 512; N = 512;
  } else if (id < 2048) {
    id -= 1024;
    src = Wf1 + (size_t)l * 1048576; dst = Wf1T + (size_t)l * 1048576;
    K = 512; N = 2048;
  } else {
    id -= 2048;
    src = Wf2 + (size_t)l * 524288;  dst = Wf2T + (size_t)l * 524288;
    K = 1024; N = 512;
  }
  const int ntn = N >> 5;
  const int n0 = (id % ntn) * 32, k0 = (id / ntn) * 32;
  const int tx = threadIdx.x & 31, ty = threadIdx.x >> 5;
#pragma unroll
  for (int r = 0; r < 32; r += 8)
    tile[ty + r][tx] = src[(size_t)(k0 + ty + r) * N + (n0 + tx)];
  __syncthreads();
#pragma unroll
  for (int r = 0; r < 32; r += 8)
    dst[(size_t)(n0 + ty + r) * K + (k0 + tx)] = f2bf(tile[tx][ty + r]);
}

// ---------------- mask -> padded float adds: maskF[l][48][48] = 0 or -1e9
__global__ __launch_bounds__(256) void maskf_kernel(const void* __restrict__ maskp,
                                                    float* __restrict__ maskF) {
  __shared__ int u8flag;
  const int l = blockIdx.x;
  const unsigned char* mu = (const unsigned char*)maskp + (size_t)l * (Sq * Sq);
  const int* mi = (const int*)maskp + (size_t)l * (Sq * Sq);
  if (threadIdx.x == 0) {
    int ok = 1;
    for (int i = 0; i < Sq; i++) ok &= (mu[i * (Sq + 1)] != 0) ? 1 : 0;
    u8flag = ok;
  }
  __syncthreads();
  const int use_u8 = u8flag;
  float* out = maskF + (size_t)l * 2304;
  for (int t = threadIdx.x; t < 2304; t += 256) {
    const int i = t / 48, j = t - i * 48;
    float v = -1e9f;
    if (i < Sq && j < Sq) {
      const int mv = use_u8 ? (int)mu[i * Sq + j] : mi[i * Sq + j];
      v = mv ? 0.f : -1e9f;
    }
    out[t] = v;
  }
}

// ---------------- fused tokenizer + LN1(layer0): one wave per token
__global__ __launch_bounds__(256) void tok_ln_kernel(const float* __restrict__ x_num,
                                                     const int* __restrict__ x_cat,
                                                     const float* __restrict__ w_num,
                                                     const float* __restrict__ b_num,
                                                     const float* __restrict__ emb_cat,
                                                     const float* __restrict__ b_cat,
                                                     const float* __restrict__ cls,
                                                     const float* __restrict__ gw,
                                                     const float* __restrict__ gb,
                                                     float* __restrict__ X,
                                                     u16* __restrict__ Hout, int c0) {
  const int wave = threadIdx.x >> 6, lane = threadIdx.x & 63;
  const int tok = blockIdx.x * 4 + wave;
  const int b   = tok / Sq;
  const int s   = tok - b * Sq;
  const int bg  = c0 + b;
  const int col0 = lane * 8;
  float v[8];
  if (s < NNq) {
    const float xv = x_num[bg * NNq + s];
    const float4 w0 = *(const float4*)(w_num + s * Dq + col0);
    const float4 w1 = *(const float4*)(w_num + s * Dq + col0 + 4);
    const float4 b0 = *(const float4*)(b_num + s * Dq + col0);
    const float4 b1 = *(const float4*)(b_num + s * Dq + col0 + 4);
    v[0]=fmaf(xv,w0.x,b0.x); v[1]=fmaf(xv,w0.y,b0.y); v[2]=fmaf(xv,w0.z,b0.z); v[3]=fmaf(xv,w0.w,b0.w);
    v[4]=fmaf(xv,w1.x,b1.x); v[5]=fmaf(xv,w1.y,b1.y); v[6]=fmaf(xv,w1.z,b1.z); v[7]=fmaf(xv,w1.w,b1.w);
  } else if (s < NNq + NCq) {
    const int j = s - NNq;
    const int row = x_cat[bg * NCq + j] + j * CARDq;
    const float4 e0 = *(const float4*)(emb_cat + (size_t)row * Dq + col0);
    const float4 e1 = *(const float4*)(emb_cat + (size_t)row * Dq + col0 + 4);
    const float4 b0 = *(const float4*)(b_cat + j * Dq + col0);
    const float4 b1 = *(const float4*)(b_cat + j * Dq + col0 + 4);
    v[0]=e0.x+b0.x; v[1]=e0.y+b0.y; v[2]=e0.z+b0.z; v[3]=e0.w+b0.w;
    v[4]=e1.x+b1.x; v[5]=e1.y+b1.y; v[6]=e1.z+b1.z; v[7]=e1.w+b1.w;
  } else {
    const float4 c0v = *(const float4*)(cls + col0);
    const float4 c1v = *(const float4*)(cls + col0 + 4);
    v[0]=c0v.x; v[1]=c0v.y; v[2]=c0v.z; v[3]=c0v.w;
    v[4]=c1v.x; v[5]=c1v.y; v[6]=c1v.z; v[7]=c1v.w;
  }
  float s1 = 0.f, s2 = 0.f;
#pragma unroll
  for (int i = 0; i < 8; i++) { s1 += v[i]; s2 += v[i] * v[i]; }
#pragma unroll
  for (int off = 32; off > 0; off >>= 1) { s1 += __shfl_xor(s1, off); s2 += __shfl_xor(s2, off); }
  const float mean = s1 * (1.0f / Dq);
  const float rstd = rsqrtf(s2 * (1.0f / Dq) - mean * mean + 1e-5f);
  float* xp = X + (size_t)tok * Dq + col0;
  *(float4*)xp       = (float4){v[0], v[1], v[2], v[3]};
  *(float4*)(xp + 4) = (float4){v[4], v[5], v[6], v[7]};
  const float* gwp = gw + col0;
  const float* gbp = gb + col0;
  u16 o[8];
#pragma unroll
  for (int i = 0; i < 8; i++) o[i] = f2bf((v[i] - mean) * rstd * gwp[i] + gbp[i]);
  uint4 pk;
  pk.x = (u32)o[0] | ((u32)o[1] << 16); pk.y = (u32)o[2] | ((u32)o[3] << 16);
  pk.z = (u32)o[4] | ((u32)o[5] << 16); pk.w = (u32)o[6] | ((u32)o[7] << 16);
  *(uint4*)(Hout + (size_t)tok * Dq + col0) = pk;
}

// ---------------- LayerNorm with row mapping
__global__ __launch_bounds__(256) void ln_kernel(const float* __restrict__ X,
                                                 const float* __restrict__ gw,
                                                 const float* __restrict__ gb,
                                                 u16* __restrict__ Hout,
                                                 int inmul, int inadd) {
  const int wave = threadIdx.x >> 6, lane = threadIdx.x & 63;
  const int row = blockIdx.x * 4 + wave;
  const size_t srow = (size_t)row * inmul + inadd;
  const float* xr = X + srow * Dq + lane * 8;
  const float4 a = *(const float4*)xr;
  const float4 b = *(const float4*)(xr + 4);
  float s  = a.x + a.y + a.z + a.w + b.x + b.y + b.z + b.w;
  float ss = a.x*a.x + a.y*a.y + a.z*a.z + a.w*a.w + b.x*b.x + b.y*b.y + b.z*b.z + b.w*b.w;
#pragma unroll
  for (int off = 32; off > 0; off >>= 1) { s += __shfl_xor(s, off); ss += __shfl_xor(ss, off); }
  const float mean = s * (1.0f / Dq);
  const float rstd = rsqrtf(ss * (1.0f / Dq) - mean * mean + 1e-5f);
  const float xv[8] = {a.x, a.y, a.z, a.w, b.x, b.y, b.z, b.w};
  const float* gwp = gw + lane * 8;
  const float* gbp = gb + lane * 8;
  u16 o[8];
#pragma unroll
  for (int i = 0; i < 8; i++) o[i] = f2bf((xv[i] - mean) * rstd * gwp[i] + gbp[i]);
  uint4 pk;
  pk.x = (u32)o[0] | ((u32)o[1] << 16); pk.y = (u32)o[2] | ((u32)o[3] << 16);
  pk.z = (u32)o[4] | ((u32)o[5] << 16); pk.w = (u32)o[6] | ((u32)o[7] << 16);
  *(uint4*)(Hout + (size_t)row * Dq + lane * 8) = pk;
}

// ---------------- GEMM: C[M,N] = A[M,K] @ Bt[N,K]^T (+bias, mode-specific epilogue)
template <int MODE>
__global__ __launch_bounds__(256) void gemm_kernel(const u16* __restrict__ A,
                                                   const u16* __restrict__ Bt0, const u16* __restrict__ Bt1, const u16* __restrict__ Bt2,
                                                   const float* __restrict__ bi0, const float* __restrict__ bi1, const float* __restrict__ bi2,
                                                   void* __restrict__ out0, void* __restrict__ out1, void* __restrict__ out2,
                                                   size_t ostride, int K, int amul, int aadd, int xmul, int xadd, int nofs) {
  __shared__ uint4 smem4[1024];   // 16 KB
  char* smem = (char*)smem4;
  const int tid  = threadIdx.x;
  const int wave = tid >> 6;
  const int lane = tid & 63;
  const int mblk = blockIdx.y;
  const int nblk = blockIdx.x;
  const u16*   Bt;
  const float* bias;
  void*        outp;
  if (MODE == 3) {
    Bt = Bt0; bias = nullptr; outp = out0;
  } else {
    const int z = blockIdx.z;
    Bt   = (z == 0) ? Bt0 : (z == 1) ? Bt1 : Bt2;
    bias = (z == 0) ? bi0 : (z == 1) ? bi1 : bi2;
    outp = (z == 0) ? out0 : (z == 1) ? out1 : out2;
  }

  const int cg   = (lane & 3) ^ ((lane >> 3) & 3);
  const int arow = wave * 32 + (lane >> 2);
  const u16* gA0 = A + ((size_t)(mblk * 128 + arow) * amul + aadd) * K + cg * 8;
  const u16* gA1 = A + ((size_t)(mblk * 128 + arow + 16) * amul + aadd) * K + cg * 8;
  char* lA0 = smem + wave * 2048;
  char* lA1 = lA0 + 1024;

  const u16 *gB0, *gB1;
  char *lB0, *lB1;
  if (MODE == 2) {
    const int brow = wave * 16 + (lane >> 2);
    gB0 = Bt + (size_t)(nblk * 64 + brow) * K + cg * 8;
    gB1 = Bt + (size_t)(FHq + nblk * 64 + brow) * K + cg * 8;
    lB0 = smem + 8192  + wave * 1024;
    lB1 = smem + 12288 + wave * 1024;
  } else {
    const int brow = wave * 32 + (lane >> 2);
    gB0 = Bt + (size_t)((nblk + nofs) * 128 + brow) * K + cg * 8;
    gB1 = gB0 + (size_t)16 * K;
    lB0 = smem + 8192 + wave * 2048;
    lB1 = lB0 + 1024;
  }

  const int slot = (lane >> 4) ^ ((lane >> 1) & 3);
  const int r16  = lane & 15;
  const int wm   = (wave >> 1) * 64;
  int aoff[4], boff[4];
#pragma unroll
  for (int i = 0; i < 4; i++) aoff[i] = (wm + i * 16 + r16) * 64 + slot * 16;
  if (MODE == 2) {
    const int wn = (wave & 1) * 32;
#pragma unroll
    for (int j = 0; j < 2; j++) {
      boff[j]     = 8192  + (wn + j * 16 + r16) * 64 + slot * 16;
      boff[2 + j] = 12288 + (wn + j * 16 + r16) * 64 + slot * 16;
    }
  } else {
    const int wn = (wave & 1) * 64;
#pragma unroll
    for (int j = 0; j < 4; j++) boff[j] = 8192 + (wn + j * 16 + r16) * 64 + slot * 16;
  }

  f32x4 acc[16];
#pragma unroll
  for (int i = 0; i < 16; i++) acc[i] = (f32x4){0.f, 0.f, 0.f, 0.f};

  const int kiter = K >> 5;
  for (int kk = 0; kk < kiter; kk++) {
    __syncthreads();
    glds16(gA0, lA0); glds16(gA1, lA1);
    glds16(gB0, lB0); glds16(gB1, lB1);
    gA0 += 32; gA1 += 32; gB0 += 32; gB1 += 32;
    __syncthreads();

    if (MODE == 2) {
      bf16x8 af[4], ba[2], bg[2];
#pragma unroll
      for (int i = 0; i < 4; i++) af[i] = *(const bf16x8*)(smem + aoff[i]);
#pragma unroll
      for (int j = 0; j < 2; j++) {
        ba[j] = *(const bf16x8*)(smem + boff[j]);
        bg[j] = *(const bf16x8*)(smem + boff[2 + j]);
      }
#pragma unroll
      for (int i = 0; i < 4; i++)
#pragma unroll
        for (int j = 0; j < 2; j++) {
          acc[i * 2 + j]     = __builtin_amdgcn_mfma_f32_16x16x32_bf16(af[i], ba[j], acc[i * 2 + j], 0, 0, 0);
          acc[8 + i * 2 + j] = __builtin_amdgcn_mfma_f32_16x16x32_bf16(af[i], bg[j], acc[8 + i * 2 + j], 0, 0, 0);
        }
    } else {
      bf16x8 af[4], bf[4];
#pragma unroll
      for (int i = 0; i < 4; i++) af[i] = *(const bf16x8*)(smem + aoff[i]);
#pragma unroll
      for (int j = 0; j < 4; j++) bf[j] = *(const bf16x8*)(smem + boff[j]);
#pragma unroll
      for (int i = 0; i < 4; i++)
#pragma unroll
        for (int j = 0; j < 4; j++)
          acc[i * 4 + j] = __builtin_amdgcn_mfma_f32_16x16x32_bf16(af[i], bf[j], acc[i * 4 + j], 0, 0, 0);
    }
  }

  const int quad = lane >> 4;
  if (MODE == 3) {
    const int nb   = nblk + nofs;
    const int buf  = nb >> 2;
    u16* C = (u16*)out0 + (size_t)buf * ostride;
    const float* biasp = (buf == 0) ? bi0 : (buf == 1) ? bi1 : bi2;
    const int colbase = (nb & 3) * 128 + (wave & 1) * 64;
#pragma unroll
    for (int j = 0; j < 4; j++) {
      const int c = colbase + j * 16 + r16;
      const float bv = biasp[c];
#pragma unroll
      for (int i = 0; i < 4; i++) {
        const int r0 = mblk * 128 + wm + i * 16 + quad * 4;
        f32x4 v = acc[i * 4 + j];
#pragma unroll
        for (int r = 0; r < 4; r++)
          C[(size_t)(r0 + r) * Dq + c] = f2bf(v[r] + bv);
      }
    }
  } else if (MODE == 1) {
    float* X = (float*)outp;
    const int wn = (wave & 1) * 64;
#pragma unroll
    for (int j = 0; j < 4; j++) {
      const int c = nblk * 128 + wn + j * 16 + r16;
      const float bv = bias[c];
#pragma unroll
      for (int i = 0; i < 4; i++) {
        const int r0 = mblk * 128 + wm + i * 16 + quad * 4;
        f32x4 v = acc[i * 4 + j];
#pragma unroll
        for (int r = 0; r < 4; r++) {
          const size_t idx = ((size_t)(r0 + r) * xmul + xadd) * Dq + c;
          X[idx] += v[r] + bv;
        }
      }
    }
  } else if (MODE == 2) {
    u16* AG = (u16*)outp;
    const int wn = (wave & 1) * 32;
#pragma unroll
    for (int j = 0; j < 2; j++) {
      const int c = nblk * 64 + wn + j * 16 + r16;
      const float bva = bias[c];
      const float bvg = bias[FHq + c];
#pragma unroll
      for (int i = 0; i < 4; i++) {
        const int r0 = mblk * 128 + wm + i * 16 + quad * 4;
        f32x4 va = acc[i * 2 + j];
        f32x4 vg = acc[8 + i * 2 + j];
#pragma unroll
        for (int r = 0; r < 4; r++) {
          const float av = va[r] + bva;
          const float gv = vg[r] + bvg;
          AG[(size_t)(r0 + r) * FHq + c] = f2bf(av * fmaxf(gv, 0.f));
        }
      }
    }
  }
}

// ---------------- MFMA sparse attention (layers 0..L-2): ONE WAVE per block.
// LDS (wave-private, 16128 B): R1 [64][72] = K-stage then V^T; R2 [48][72] = Q-stage then P.
// All Q/K/V global reads coalesced (8 rows x 128 B per wave-iter); frags come from LDS.
__global__ __launch_bounds__(64) void attn_mfma_kernel(const u16* __restrict__ Q,
                                                       const u16* __restrict__ K,
                                                       const u16* __restrict__ V,
                                                       const float* __restrict__ maskF,
                                                       u16* __restrict__ O) {
  __shared__ u16 lds[8064];
  u16* R1 = lds;          // 64*72 u16 = 9216 B
  u16* R2 = lds + 4608;   // 48*72 u16 = 6912 B
  const int lane = threadIdx.x;
  const int b = blockIdx.x >> 3;
  const int h = blockIdx.x & 7;
  const size_t hbase = (size_t)b * (Sq * Dq) + (size_t)h * 64;
  const int r16 = lane & 15, quad = lane >> 4;

  // 1. coalesced global loads into regs; Q,K -> LDS stage
  uint4 qreg[5], kreg[5], vreg[5];
#pragma unroll
  for (int it = 0; it < 5; it++) {
    const int t = lane + it * 64;
    if (t < 264) {
      const int j = t >> 3, ck = t & 7;
      const size_t off = hbase + (size_t)j * Dq + ck * 8;
      qreg[it] = *(const uint4*)(Q + off);
      kreg[it] = *(const uint4*)(K + off);
      vreg[it] = *(const uint4*)(V + off);
    }
  }
#pragma unroll
  for (int it = 0; it < 5; it++) {
    const int t = lane + it * 64;
    if (t < 264) {
      const int j = t >> 3, ck = t & 7;
      *(uint4*)(R1 + j * 72 + ck * 8) = kreg[it];
      *(uint4*)(R2 + j * 72 + ck * 8) = qreg[it];
    }
  }
  __syncthreads();

  // 2. Q/K fragments from LDS (rows clamped to 32)
  bf16x8 qf[3][2], kf[3][2];
#pragma unroll
  for (int m = 0; m < 3; m++) {
    const int rl = (m * 16 + r16 < Sq) ? (m * 16 + r16) : (Sq - 1);
#pragma unroll
    for (int kk = 0; kk < 2; kk++) {
      qf[m][kk] = *(const bf16x8*)(R2 + rl * 72 + kk * 32 + quad * 8);
      kf[m][kk] = *(const bf16x8*)(R1 + rl * 72 + kk * 32 + quad * 8);
    }
  }
  __syncthreads();

  // 3. zero R1 (V^T pads), scatter V^T, zero P pad cols 48..63
  const uint4 z4 = {0u, 0u, 0u, 0u};
#pragma unroll
  for (int it = 0; it < 9; it++) ((uint4*)R1)[lane + it * 64];  // touch nothing — removed
#pragma unroll
  for (int it = 0; it < 9; it++) {
    const int t = lane + it * 64;
    if (t < 576) ((uint4*)R1)[t] = z4;
  }
#pragma unroll
  for (int it = 0; it < 5; it++) {
    const int t = lane + it * 64;
    if (t < 264) {
      const int j = t >> 3, ck = t & 7;
      const u16* sp = (const u16*)&vreg[it];
#pragma unroll
      for (int e = 0; e < 8; e++) R1[(ck * 8 + e) * 72 + j] = sp[e];
    }
  }
#pragma unroll
  for (int it = 0; it < 2; it++) {
    const int t = lane + it * 64;
    if (t < 96) {
      const int row = t >> 1, half = t & 1;
      *(uint4*)(R2 + row * 72 + 48 + half * 8) = z4;
    }
  }

  // 4. QK^T MFMA
  f32x4 acc[3][3];
#pragma unroll
  for (int m = 0; m < 3; m++)
#pragma unroll
    for (int n = 0; n < 3; n++) acc[m][n] = (f32x4){0.f, 0.f, 0.f, 0.f};
#pragma unroll
  for (int kk = 0; kk < 2; kk++)
#pragma unroll
    for (int m = 0; m < 3; m++)
#pragma unroll
      for (int n = 0; n < 3; n++)
        acc[m][n] = __builtin_amdgcn_mfma_f32_16x16x32_bf16(qf[m][kk], kf[n][kk], acc[m][n], 0, 0, 0);

  // 5. softmax (unnormalized), write P to R2 (cols 0..47; cols 33..47 exp->0 via maskF)
  float linv[3][4];
#pragma unroll
  for (int m = 0; m < 3; m++) {
    float v[3][4];
#pragma unroll
    for (int n = 0; n < 3; n++) {
      const int c = n * 16 + r16;
#pragma unroll
      for (int r = 0; r < 4; r++) {
        const int R = m * 16 + quad * 4 + r;
        v[n][r] = acc[m][n][r] * 0.125f + maskF[R * 48 + c];
      }
    }
    float mr[4], sum[4];
#pragma unroll
    for (int r = 0; r < 4; r++) {
      mr[r] = fmaxf(fmaxf(v[0][r], v[1][r]), v[2][r]);
#pragma unroll
      for (int off = 8; off > 0; off >>= 1) mr[r] = fmaxf(mr[r], __shfl_xor(mr[r], off));
      sum[r] = 0.f;
    }
#pragma unroll
    for (int n = 0; n < 3; n++)
#pragma unroll
      for (int r = 0; r < 4; r++) { v[n][r] = __expf(v[n][r] - mr[r]); sum[r] += v[n][r]; }
#pragma unroll
    for (int r = 0; r < 4; r++) {
#pragma unroll
      for (int off = 8; off > 0; off >>= 1) sum[r] += __shfl_xor(sum[r], off);
      linv[m][r] = 1.0f / sum[r];
    }
#pragma unroll
    for (int n = 0; n < 3; n++)
#pragma unroll
      for (int r = 0; r < 4; r++)
        R2[(m * 16 + quad * 4 + r) * 72 + n * 16 + r16] = f2bf(v[n][r]);
  }
  __syncthreads();

  // 6. O = P * V^T
  bf16x8 pa[3][2], vb[4][2];
#pragma unroll
  for (int m = 0; m < 3; m++)
#pragma unroll
    for (int kk = 0; kk < 2; kk++)
      pa[m][kk] = *(const bf16x8*)(R2 + (m * 16 + r16) * 72 + kk * 32 + quad * 8);
#pragma unroll
  for (int n = 0; n < 4; n++)
#pragma unroll
    for (int kk = 0; kk < 2; kk++)
      vb[n][kk] = *(const bf16x8*)(R1 + (n * 16 + r16) * 72 + kk * 32 + quad * 8);
  f32x4 o[3][4];
#pragma unroll
  for (int m = 0; m < 3; m++)
#pragma unroll
    for (int n = 0; n < 4; n++) o[m][n] = (f32x4){0.f, 0.f, 0.f, 0.f};
#pragma unroll
  for (int kk = 0; kk < 2; kk++)
#pragma unroll
    for (int m = 0; m < 3; m++)
#pragma unroll
      for (int n = 0; n < 4; n++)
        o[m][n] = __builtin_amdgcn_mfma_f32_16x16x32_bf16(pa[m][kk], vb[n][kk], o[m][n], 0, 0, 0);

#pragma unroll
  for (int m = 0; m < 3; m++)
#pragma unroll
    for (int r = 0; r < 4; r++) {
      const int i = m * 16 + quad * 4 + r;
      if (i < Sq) {
#pragma unroll
        for (int n = 0; n < 4; n++)
          O[hbase + (size_t)i * Dq + n * 16 + r16] = f2bf(o[m][n][r] * linv[m][r]);
      }
    }
}

// ---------------- last-layer CLS-only attention: one wave per (b,h).
__global__ __launch_bounds__(256) void attn_cls_kernel(const u16* __restrict__ Qc,
                                                       const u16* __restrict__ Kf,
                                                       const u16* __restrict__ Vf,
                                                       u16* __restrict__ Oc) {
  __shared__ u16 lds[4][4432];
  __shared__ float psh[4][40];
  const int wave = threadIdx.x >> 6, lane = threadIdx.x & 63;
  const int b = blockIdx.x >> 1;
  const int h = (blockIdx.x & 1) * 4 + wave;
  u16* Kl = &lds[wave][0];
  u16* Vl = &lds[wave][2178];
  u16* ql = &lds[wave][4360];
  const size_t hbase = (size_t)b * (Sq * Dq) + (size_t)h * 64;

  for (int t = lane; t < 528; t += 64) {
    const int mtx = (t >= 264) ? 1 : 0;
    const int e = t - mtx * 264;
    const int j = e >> 3, ck = e & 7;
    const uint4 v = *(const uint4*)((mtx ? Vf : Kf) + hbase + (size_t)j * Dq + ck * 8);
    u16* dst = (mtx ? Vl : Kl) + j * 66 + ck * 8;
    const u16* sp = (const u16*)&v;
#pragma unroll
    for (int e2 = 0; e2 < 8; e2++) dst[e2] = sp[e2];
  }
  if (lane < 8)
    *(uint4*)(ql + lane * 8) = *(const uint4*)(Qc + (size_t)b * Dq + h * 64 + lane * 8);
  __syncthreads();

  float p;
  if (lane < Sq) {
    float s = 0.f;
#pragma unroll 16
    for (int d = 0; d < 64; d++) s += bf2f(ql[d]) * bf2f(Kl[lane * 66 + d]);
    p = s * 0.125f;
  } else p = -3e38f;
  float mx = p;
#pragma unroll
  for (int off = 32; off > 0; off >>= 1) mx = fmaxf(mx, __shfl_xor(mx, off));
  float e = (lane < Sq) ? __expf(p - mx) : 0.f;
  float sum = e;
#pragma unroll
  for (int off = 32; off > 0; off >>= 1) sum += __shfl_xor(sum, off);
  if (lane < Sq) psh[wave][lane] = e / sum;
  __syncthreads();

  float o = 0.f;
#pragma unroll
  for (int j = 0; j < Sq; j++) o += psh[wave][j] * bf2f(Vl[j * 66 + lane]);
  Oc[(size_t)b * Dq + h * 64 + lane] = f2bf(o);
}

// ---------------- head: LN(CLS) -> relu -> dot Wh + bh, one wave per sample
__global__ __launch_bounds__(256) void head_kernel(const float* __restrict__ X,
                                                   const float* __restrict__ hw, const float* __restrict__ hb,
                                                   const float* __restrict__ Wh, const float* __restrict__ bh,
                                                   float* __restrict__ out) {
  const int wave = threadIdx.x >> 6, lane = threadIdx.x & 63;
  const int b = blockIdx.x * 4 + wave;
  const float* xr = X + ((size_t)b * Sq + (Sq - 1)) * Dq + lane * 8;
  const float4 a  = *(const float4*)xr;
  const float4 bb = *(const float4*)(xr + 4);
  const float xv[8] = {a.x, a.y, a.z, a.w, bb.x, bb.y, bb.z, bb.w};
  float s = 0.f, ss = 0.f;
#pragma unroll
  for (int i = 0; i < 8; i++) { s += xv[i]; ss += xv[i] * xv[i]; }
#pragma unroll
  for (int off = 32; off > 0; off >>= 1) { s += __shfl_xor(s, off); ss += __shfl_xor(ss, off); }
  const float mean = s * (1.0f / Dq);
  const float rstd = rsqrtf(ss * (1.0f / Dq) - mean * mean + 1e-5f);
  float part = 0.f;
#pragma unroll
  for (int i = 0; i < 8; i++) {
    const float c = (xv[i] - mean) * rstd * hw[lane * 8 + i] + hb[lane * 8 + i];
    part += fmaxf(c, 0.f) * Wh[lane * 8 + i];
  }
#pragma unroll
  for (int off = 32; off > 0; off >>= 1) part += __shfl_xor(part, off);
  if (lane == 0) out[b] = part + bh[0];
}

extern "C" void kernel_launch(void* const* d_in, const int* in_sizes, int n_in,
                              void* d_out, int out_size, void* d_ws, size_t ws_size,
                              hipStream_t stream) {
  (void)in_sizes; (void)n_in; (void)out_size;
  const float* x_num   = (const float*)d_in[0];
  const int*   x_cat   = (const int*)d_in[1];
  const float* w_num   = (const float*)d_in[2];
  const float* b_num   = (const float*)d_in[3];
  const float* emb_cat = (const float*)d_in[4];
  const float* b_cat   = (const float*)d_in[5];
  const float* cls     = (const float*)d_in[6];
  const float* ln1_w   = (const float*)d_in[7];
  const float* ln1_b   = (const float*)d_in[8];
  const float* Wq      = (const float*)d_in[9];
  const float* bq      = (const float*)d_in[10];
  const float* Wk      = (const float*)d_in[11];
  const float* bk      = (const float*)d_in[12];
  const float* Wv      = (const float*)d_in[13];
  const float* bv      = (const float*)d_in[14];
  const float* Wo      = (const float*)d_in[15];
  const float* bo      = (const float*)d_in[16];
  const float* ln2_w   = (const float*)d_in[17];
  const float* ln2_b   = (const float*)d_in[18];
  const float* Wf1     = (const float*)d_in[19];
  const float* bf1     = (const float*)d_in[20];
  const float* Wf2     = (const float*)d_in[21];
  const float* bf2     = (const float*)d_in[22];
  const void*  mask    = d_in[23];
  const float* hln_w   = (const float*)d_in[25];
  const float* hln_b   = (const float*)d_in[26];
  const float* Wh      = (const float*)d_in[27];
  const float* bhp     = (const float*)d_in[28];
  float* out = (float*)d_out;

  const size_t WBYTES = 15728640ULL;
  const size_t MFB    = 27648ULL;
  int Bc = Bq;
  while (Bc > 128) {
    const size_t need = WBYTES + MFB + (size_t)Bc * Sq * 6144ULL;
    if (need <= ws_size) break;
    Bc >>= 1;
  }
  const size_t Mc = (size_t)Bc * Sq;

  char* ws = (char*)d_ws;
  u16* Wbase = (u16*)ws;
  float* maskF = (float*)(ws + WBYTES);
  float* X   = (float*)(ws + WBYTES + MFB);
  u16* Hb    = (u16*)((char*)X + Mc * 2048);
  u16* Qb    = (u16*)((char*)Hb + Mc * 1024);
  u16* Kb    = Qb + Mc * 512;
  u16* Vb    = Kb + Mc * 512;
  u16* AGb   = Qb;

  u16* WqkvT = Wbase;
  u16* WoT   = WqkvT + 2359296;
  u16* Wf1T  = WoT   + 786432;
  u16* Wf2T  = Wf1T  + 3145728;

  wconv_all_kernel<<<dim3(2560, 3), 256, 0, stream>>>(Wq, Wk, Wv, Wo, Wf1, Wf2,
                                                      WqkvT, WoT, Wf1T, Wf2T);
  maskf_kernel<<<Lq, 256, 0, stream>>>(mask, maskF);

  const int mb  = (int)(Mc / 128);
  const int mbC = Bc / 128;

  for (int c0 = 0; c0 < Bq; c0 += Bc) {
    tok_ln_kernel<<<(int)(Mc / 4), 256, 0, stream>>>(x_num, x_cat, w_num, b_num, emb_cat, b_cat, cls,
                                                     ln1_w, ln1_b, X, Hb, c0);

    for (int l = 0; l < Lq; l++) {
      if (l < Lq - 1) {
        gemm_kernel<3><<<dim3(12, mb, 1), 256, 0, stream>>>(Hb,
            WqkvT + l * 786432, nullptr, nullptr,
            bq + l * 512, bk + l * 512, bv + l * 512,
            Qb, nullptr, nullptr, Mc * 512, 512, 1, 0, 1, 0, 0);
        attn_mfma_kernel<<<Bc * 8, 64, 0, stream>>>(Qb, Kb, Vb, maskF + l * 2304, Hb);
        gemm_kernel<1><<<dim3(4, mb, 1), 256, 0, stream>>>(Hb,
            WoT + l * 262144, WoT + l * 262144, WoT + l * 262144,
            bo + l * 512, bo + l * 512, bo + l * 512,
            X, X, X, 0, 512, 1, 0, 1, 0, 0);
        ln_kernel<<<(int)(Mc / 4), 256, 0, stream>>>(X, ln2_w + l * 512, ln2_b + l * 512, Hb, 1, 0);
        gemm_kernel<2><<<dim3(16, mb, 1), 256, 0, stream>>>(Hb,
            Wf1T + l * 1048576, Wf1T + l * 1048576, Wf1T + l * 1048576,
            bf1 + l * 2048, bf1 + l * 2048, bf1 + l * 2048,
            AGb, AGb, AGb, 0, 512, 1, 0, 1, 0, 0);
        gemm_kernel<1><<<dim3(4, mb, 1), 256, 0, stream>>>(AGb,
            Wf2T + l * 524288, Wf2T + l * 524288, Wf2T + l * 524288,
            bf2 + l * 512, bf2 + l * 512, bf2 + l * 512,
            X, X, X, 0, 1024, 1, 0, 1, 0, 0);
        ln_kernel<<<(int)(Mc / 4), 256, 0, stream>>>(X, ln1_w + (l + 1) * 512, ln1_b + (l + 1) * 512, Hb, 1, 0);
      } else {
        gemm_kernel<3><<<dim3(8, mb, 1), 256, 0, stream>>>(Hb,
            WqkvT + l * 786432, nullptr, nullptr,
            bq + l * 512, bk + l * 512, bv + l * 512,
            Qb, nullptr, nullptr, Mc * 512, 512, 1, 0, 1, 0, 4);
        gemm_kernel<3><<<dim3(4, mbC, 1), 256, 0, stream>>>(Hb,
            WqkvT + l * 786432, nullptr, nullptr,
            bq + l * 512, bk + l * 512, bv + l * 512,
            Qb, nullptr, nullptr, Mc * 512, 512, Sq, Sq - 1, 1, 0, 0);
        attn_cls_kernel<<<Bc * 2, 256, 0, stream>>>(Qb, Kb, Vb, Hb);
        gemm_kernel<1><<<dim3(4, mbC, 1), 256, 0, stream>>>(Hb,
            WoT + l * 262144, WoT + l * 262144, WoT + l * 262144,
            bo + l * 512, bo + l * 512, bo + l * 512,
            X, X, X, 0, 512, 1, 0, Sq, Sq - 1, 0);
        ln_kernel<<<Bc / 4, 256, 0, stream>>>(X, ln2_w + l * 512, ln2_b + l * 512, Kb, Sq, Sq - 1);
        gemm_kernel<2><<<dim3(16, mbC, 1), 256, 0, stream>>>(Kb,
            Wf1T + l * 1048576, Wf1T + l * 1048576, Wf1T + l * 1048576,
            bf1 + l * 2048, bf1 + l * 2048, bf1 + l * 2048,
            AGb, AGb, AGb, 0, 512, 1, 0, 1, 0, 0);
        gemm_kernel<1><<<dim3(4, mbC, 1), 256, 0, stream>>>(AGb,
            Wf2T + l * 524288, Wf2T + l * 524288, Wf2T + l * 524288,
            bf2 + l * 512, bf2 + l * 512, bf2 + l * 512,
            X, X, X, 0, 1024, 1, 0, Sq, Sq - 1, 0);
      }
    }
    head_kernel<<<Bc / 4, 256, 0, stream>>>(X, hln_w, hln_b, Wh, bhp, out + c0);
  }
}

// Round 12
// 2013.576 us; speedup vs baseline: 1.0517x; 1.0517x over previous
//
#include <hip/hip_runtime.h>
#include <stdint.h>

#define Bq    2048
#define NNq   24
#define NCq   8
#define CARDq 16
#define Dq    512
#define Hq    8
#define Lq    3
#define FHq   1024
#define Sq    33

typedef unsigned short u16;
typedef unsigned int   u32;
typedef __bf16 bf16x8 __attribute__((ext_vector_type(8)));
typedef float  f32x4  __attribute__((ext_vector_type(4)));

__device__ __forceinline__ u16 f2bf(float f) {   // native v_cvt (RNE)
  return __builtin_bit_cast(u16, (__bf16)f);
}
__device__ __forceinline__ float bf2f(u16 h) {
  u32 u = ((u32)h) << 16;
  return __builtin_bit_cast(float, u);
}

__device__ __forceinline__ void glds16(const void* g, void* l) {
  __builtin_amdgcn_global_load_lds((const __attribute__((address_space(1))) void*)g,
                                   (__attribute__((address_space(3))) void*)l, 16, 0, 0);
}

// ---------------- ALL weight transposes + f32->bf16 in ONE dispatch
__global__ __launch_bounds__(256) void wconv_all_kernel(const float* __restrict__ Wq,
                                                        const float* __restrict__ Wk,
                                                        const float* __restrict__ Wv,
                                                        const float* __restrict__ Wo,
                                                        const float* __restrict__ Wf1,
                                                        const float* __restrict__ Wf2,
                                                        u16* __restrict__ WqkvT,
                                                        u16* __restrict__ WoT,
                                                        u16* __restrict__ Wf1T,
                                                        u16* __restrict__ Wf2T) {
  __shared__ float tile[32][33];
  const int l = blockIdx.y;
  int id = blockIdx.x;
  const float* src; u16* dst; int K, N;
  if (id < 768) {
    const int m = id >> 8; id &= 255;
    src = ((m == 0) ? Wq : (m == 1) ? Wk : Wv) + (size_t)l * 262144;
    dst = WqkvT + (size_t)l * 786432 + (size_t)m * 262144;
    K = 512; N = 512;
  } else if (id < 1024) {
    id -= 768;
    src = Wo + (size_t)l * 262144;  dst = WoT + (size_t)l * 262144;
    K = 512; N = 512;
  } else if (id < 2048) {
    id -= 1024;
    src = Wf1 + (size_t)l * 1048576; dst = Wf1T + (size_t)l * 1048576;
    K = 512; N = 2048;
  } else {
    id -= 2048;
    src = Wf2 + (size_t)l * 524288;  dst = Wf2T + (size_t)l * 524288;
    K = 1024; N = 512;
  }
  const int ntn = N >> 5;
  const int n0 = (id % ntn) * 32, k0 = (id / ntn) * 32;
  const int tx = threadIdx.x & 31, ty = threadIdx.x >> 5;
#pragma unroll
  for (int r = 0; r < 32; r += 8)
    tile[ty + r][tx] = src[(size_t)(k0 + ty + r) * N + (n0 + tx)];
  __syncthreads();
#pragma unroll
  for (int r = 0; r < 32; r += 8)
    dst[(size_t)(n0 + ty + r) * K + (k0 + tx)] = f2bf(tile[tx][ty + r]);
}

// ---------------- mask -> padded float adds: maskF[l][48][48] = 0 or -1e9
__global__ __launch_bounds__(256) void maskf_kernel(const void* __restrict__ maskp,
                                                    float* __restrict__ maskF) {
  __shared__ int u8flag;
  const int l = blockIdx.x;
  const unsigned char* mu = (const unsigned char*)maskp + (size_t)l * (Sq * Sq);
  const int* mi = (const int*)maskp + (size_t)l * (Sq * Sq);
  if (threadIdx.x == 0) {
    int ok = 1;
    for (int i = 0; i < Sq; i++) ok &= (mu[i * (Sq + 1)] != 0) ? 1 : 0;
    u8flag = ok;
  }
  __syncthreads();
  const int use_u8 = u8flag;
  float* out = maskF + (size_t)l * 2304;
  for (int t = threadIdx.x; t < 2304; t += 256) {
    const int i = t / 48, j = t - i * 48;
    float v = -1e9f;
    if (i < Sq && j < Sq) {
      const int mv = use_u8 ? (int)mu[i * Sq + j] : mi[i * Sq + j];
      v = mv ? 0.f : -1e9f;
    }
    out[t] = v;
  }
}

// ---------------- fused tokenizer + LN1(layer0): one wave per token
__global__ __launch_bounds__(256) void tok_ln_kernel(const float* __restrict__ x_num,
                                                     const int* __restrict__ x_cat,
                                                     const float* __restrict__ w_num,
                                                     const float* __restrict__ b_num,
                                                     const float* __restrict__ emb_cat,
                                                     const float* __restrict__ b_cat,
                                                     const float* __restrict__ cls,
                                                     const float* __restrict__ gw,
                                                     const float* __restrict__ gb,
                                                     float* __restrict__ X,
                                                     u16* __restrict__ Hout, int c0) {
  const int wave = threadIdx.x >> 6, lane = threadIdx.x & 63;
  const int tok = blockIdx.x * 4 + wave;
  const int b   = tok / Sq;
  const int s   = tok - b * Sq;
  const int bg  = c0 + b;
  const int col0 = lane * 8;
  float v[8];
  if (s < NNq) {
    const float xv = x_num[bg * NNq + s];
    const float4 w0 = *(const float4*)(w_num + s * Dq + col0);
    const float4 w1 = *(const float4*)(w_num + s * Dq + col0 + 4);
    const float4 b0 = *(const float4*)(b_num + s * Dq + col0);
    const float4 b1 = *(const float4*)(b_num + s * Dq + col0 + 4);
    v[0]=fmaf(xv,w0.x,b0.x); v[1]=fmaf(xv,w0.y,b0.y); v[2]=fmaf(xv,w0.z,b0.z); v[3]=fmaf(xv,w0.w,b0.w);
    v[4]=fmaf(xv,w1.x,b1.x); v[5]=fmaf(xv,w1.y,b1.y); v[6]=fmaf(xv,w1.z,b1.z); v[7]=fmaf(xv,w1.w,b1.w);
  } else if (s < NNq + NCq) {
    const int j = s - NNq;
    const int row = x_cat[bg * NCq + j] + j * CARDq;
    const float4 e0 = *(const float4*)(emb_cat + (size_t)row * Dq + col0);
    const float4 e1 = *(const float4*)(emb_cat + (size_t)row * Dq + col0 + 4);
    const float4 b0 = *(const float4*)(b_cat + j * Dq + col0);
    const float4 b1 = *(const float4*)(b_cat + j * Dq + col0 + 4);
    v[0]=e0.x+b0.x; v[1]=e0.y+b0.y; v[2]=e0.z+b0.z; v[3]=e0.w+b0.w;
    v[4]=e1.x+b1.x; v[5]=e1.y+b1.y; v[6]=e1.z+b1.z; v[7]=e1.w+b1.w;
  } else {
    const float4 c0v = *(const float4*)(cls + col0);
    const float4 c1v = *(const float4*)(cls + col0 + 4);
    v[0]=c0v.x; v[1]=c0v.y; v[2]=c0v.z; v[3]=c0v.w;
    v[4]=c1v.x; v[5]=c1v.y; v[6]=c1v.z; v[7]=c1v.w;
  }
  float s1 = 0.f, s2 = 0.f;
#pragma unroll
  for (int i = 0; i < 8; i++) { s1 += v[i]; s2 += v[i] * v[i]; }
#pragma unroll
  for (int off = 32; off > 0; off >>= 1) { s1 += __shfl_xor(s1, off); s2 += __shfl_xor(s2, off); }
  const float mean = s1 * (1.0f / Dq);
  const float rstd = rsqrtf(s2 * (1.0f / Dq) - mean * mean + 1e-5f);
  float* xp = X + (size_t)tok * Dq + col0;
  *(float4*)xp       = (float4){v[0], v[1], v[2], v[3]};
  *(float4*)(xp + 4) = (float4){v[4], v[5], v[6], v[7]};
  const float* gwp = gw + col0;
  const float* gbp = gb + col0;
  u16 o[8];
#pragma unroll
  for (int i = 0; i < 8; i++) o[i] = f2bf((v[i] - mean) * rstd * gwp[i] + gbp[i]);
  uint4 pk;
  pk.x = (u32)o[0] | ((u32)o[1] << 16); pk.y = (u32)o[2] | ((u32)o[3] << 16);
  pk.z = (u32)o[4] | ((u32)o[5] << 16); pk.w = (u32)o[6] | ((u32)o[7] << 16);
  *(uint4*)(Hout + (size_t)tok * Dq + col0) = pk;
}

// ---------------- LayerNorm with row mapping
__global__ __launch_bounds__(256) void ln_kernel(const float* __restrict__ X,
                                                 const float* __restrict__ gw,
                                                 const float* __restrict__ gb,
                                                 u16* __restrict__ Hout,
                                                 int inmul, int inadd) {
  const int wave = threadIdx.x >> 6, lane = threadIdx.x & 63;
  const int row = blockIdx.x * 4 + wave;
  const size_t srow = (size_t)row * inmul + inadd;
  const float* xr = X + srow * Dq + lane * 8;
  const float4 a = *(const float4*)xr;
  const float4 b = *(const float4*)(xr + 4);
  float s  = a.x + a.y + a.z + a.w + b.x + b.y + b.z + b.w;
  float ss = a.x*a.x + a.y*a.y + a.z*a.z + a.w*a.w + b.x*b.x + b.y*b.y + b.z*b.z + b.w*b.w;
#pragma unroll
  for (int off = 32; off > 0; off >>= 1) { s += __shfl_xor(s, off); ss += __shfl_xor(ss, off); }
  const float mean = s * (1.0f / Dq);
  const float rstd = rsqrtf(ss * (1.0f / Dq) - mean * mean + 1e-5f);
  const float xv[8] = {a.x, a.y, a.z, a.w, b.x, b.y, b.z, b.w};
  const float* gwp = gw + lane * 8;
  const float* gbp = gb + lane * 8;
  u16 o[8];
#pragma unroll
  for (int i = 0; i < 8; i++) o[i] = f2bf((xv[i] - mean) * rstd * gwp[i] + gbp[i]);
  uint4 pk;
  pk.x = (u32)o[0] | ((u32)o[1] << 16); pk.y = (u32)o[2] | ((u32)o[3] << 16);
  pk.z = (u32)o[4] | ((u32)o[5] << 16); pk.w = (u32)o[6] | ((u32)o[7] << 16);
  *(uint4*)(Hout + (size_t)row * Dq + lane * 8) = pk;
}

// ---------------- GEMM: C[M,N] = A[M,K] @ Bt[N,K]^T (+bias, mode-specific epilogue)
template <int MODE>
__global__ __launch_bounds__(256) void gemm_kernel(const u16* __restrict__ A,
                                                   const u16* __restrict__ Bt0, const u16* __restrict__ Bt1, const u16* __restrict__ Bt2,
                                                   const float* __restrict__ bi0, const float* __restrict__ bi1, const float* __restrict__ bi2,
                                                   void* __restrict__ out0, void* __restrict__ out1, void* __restrict__ out2,
                                                   size_t ostride, int K, int amul, int aadd, int xmul, int xadd, int nofs) {
  __shared__ uint4 smem4[1024];   // 16 KB
  char* smem = (char*)smem4;
  const int tid  = threadIdx.x;
  const int wave = tid >> 6;
  const int lane = tid & 63;
  const int mblk = blockIdx.y;
  const int nblk = blockIdx.x;
  const u16*   Bt;
  const float* bias;
  void*        outp;
  if (MODE == 3) {
    Bt = Bt0; bias = nullptr; outp = out0;
  } else {
    const int z = blockIdx.z;
    Bt   = (z == 0) ? Bt0 : (z == 1) ? Bt1 : Bt2;
    bias = (z == 0) ? bi0 : (z == 1) ? bi1 : bi2;
    outp = (z == 0) ? out0 : (z == 1) ? out1 : out2;
  }

  const int cg   = (lane & 3) ^ ((lane >> 3) & 3);
  const int arow = wave * 32 + (lane >> 2);
  const u16* gA0 = A + ((size_t)(mblk * 128 + arow) * amul + aadd) * K + cg * 8;
  const u16* gA1 = A + ((size_t)(mblk * 128 + arow + 16) * amul + aadd) * K + cg * 8;
  char* lA0 = smem + wave * 2048;
  char* lA1 = lA0 + 1024;

  const u16 *gB0, *gB1;
  char *lB0, *lB1;
  if (MODE == 2) {
    const int brow = wave * 16 + (lane >> 2);
    gB0 = Bt + (size_t)(nblk * 64 + brow) * K + cg * 8;
    gB1 = Bt + (size_t)(FHq + nblk * 64 + brow) * K + cg * 8;
    lB0 = smem + 8192  + wave * 1024;
    lB1 = smem + 12288 + wave * 1024;
  } else {
    const int brow = wave * 32 + (lane >> 2);
    gB0 = Bt + (size_t)((nblk + nofs) * 128 + brow) * K + cg * 8;
    gB1 = gB0 + (size_t)16 * K;
    lB0 = smem + 8192 + wave * 2048;
    lB1 = lB0 + 1024;
  }

  const int slot = (lane >> 4) ^ ((lane >> 1) & 3);
  const int r16  = lane & 15;
  const int wm   = (wave >> 1) * 64;
  int aoff[4], boff[4];
#pragma unroll
  for (int i = 0; i < 4; i++) aoff[i] = (wm + i * 16 + r16) * 64 + slot * 16;
  if (MODE == 2) {
    const int wn = (wave & 1) * 32;
#pragma unroll
    for (int j = 0; j < 2; j++) {
      boff[j]     = 8192  + (wn + j * 16 + r16) * 64 + slot * 16;
      boff[2 + j] = 12288 + (wn + j * 16 + r16) * 64 + slot * 16;
    }
  } else {
    const int wn = (wave & 1) * 64;
#pragma unroll
    for (int j = 0; j < 4; j++) boff[j] = 8192 + (wn + j * 16 + r16) * 64 + slot * 16;
  }

  f32x4 acc[16];
#pragma unroll
  for (int i = 0; i < 16; i++) acc[i] = (f32x4){0.f, 0.f, 0.f, 0.f};

  const int kiter = K >> 5;
  for (int kk = 0; kk < kiter; kk++) {
    __syncthreads();
    glds16(gA0, lA0); glds16(gA1, lA1);
    glds16(gB0, lB0); glds16(gB1, lB1);
    gA0 += 32; gA1 += 32; gB0 += 32; gB1 += 32;
    __syncthreads();

    if (MODE == 2) {
      bf16x8 af[4], ba[2], bg[2];
#pragma unroll
      for (int i = 0; i < 4; i++) af[i] = *(const bf16x8*)(smem + aoff[i]);
#pragma unroll
      for (int j = 0; j < 2; j++) {
        ba[j] = *(const bf16x8*)(smem + boff[j]);
        bg[j] = *(const bf16x8*)(smem + boff[2 + j]);
      }
#pragma unroll
      for (int i = 0; i < 4; i++)
#pragma unroll
        for (int j = 0; j < 2; j++) {
          acc[i * 2 + j]     = __builtin_amdgcn_mfma_f32_16x16x32_bf16(af[i], ba[j], acc[i * 2 + j], 0, 0, 0);
          acc[8 + i * 2 + j] = __builtin_amdgcn_mfma_f32_16x16x32_bf16(af[i], bg[j], acc[8 + i * 2 + j], 0, 0, 0);
        }
    } else {
      bf16x8 af[4], bf[4];
#pragma unroll
      for (int i = 0; i < 4; i++) af[i] = *(const bf16x8*)(smem + aoff[i]);
#pragma unroll
      for (int j = 0; j < 4; j++) bf[j] = *(const bf16x8*)(smem + boff[j]);
#pragma unroll
      for (int i = 0; i < 4; i++)
#pragma unroll
        for (int j = 0; j < 4; j++)
          acc[i * 4 + j] = __builtin_amdgcn_mfma_f32_16x16x32_bf16(af[i], bf[j], acc[i * 4 + j], 0, 0, 0);
    }
  }

  const int quad = lane >> 4;
  if (MODE == 3) {
    const int nb   = nblk + nofs;
    const int buf  = nb >> 2;
    u16* C = (u16*)out0 + (size_t)buf * ostride;
    const float* biasp = (buf == 0) ? bi0 : (buf == 1) ? bi1 : bi2;
    const int colbase = (nb & 3) * 128 + (wave & 1) * 64;
#pragma unroll
    for (int j = 0; j < 4; j++) {
      const int c = colbase + j * 16 + r16;
      const float bv = biasp[c];
#pragma unroll
      for (int i = 0; i < 4; i++) {
        const int r0 = mblk * 128 + wm + i * 16 + quad * 4;
        f32x4 v = acc[i * 4 + j];
#pragma unroll
        for (int r = 0; r < 4; r++)
          C[(size_t)(r0 + r) * Dq + c] = f2bf(v[r] + bv);
      }
    }
  } else if (MODE == 1) {
    float* X = (float*)outp;
    const int wn = (wave & 1) * 64;
#pragma unroll
    for (int j = 0; j < 4; j++) {
      const int c = nblk * 128 + wn + j * 16 + r16;
      const float bv = bias[c];
#pragma unroll
      for (int i = 0; i < 4; i++) {
        const int r0 = mblk * 128 + wm + i * 16 + quad * 4;
        f32x4 v = acc[i * 4 + j];
#pragma unroll
        for (int r = 0; r < 4; r++) {
          const size_t idx = ((size_t)(r0 + r) * xmul + xadd) * Dq + c;
          X[idx] += v[r] + bv;
        }
      }
    }
  } else if (MODE == 2) {
    u16* AG = (u16*)outp;
    const int wn = (wave & 1) * 32;
#pragma unroll
    for (int j = 0; j < 2; j++) {
      const int c = nblk * 64 + wn + j * 16 + r16;
      const float bva = bias[c];
      const float bvg = bias[FHq + c];
#pragma unroll
      for (int i = 0; i < 4; i++) {
        const int r0 = mblk * 128 + wm + i * 16 + quad * 4;
        f32x4 va = acc[i * 2 + j];
        f32x4 vg = acc[8 + i * 2 + j];
#pragma unroll
        for (int r = 0; r < 4; r++) {
          const float av = va[r] + bva;
          const float gv = vg[r] + bvg;
          AG[(size_t)(r0 + r) * FHq + c] = f2bf(av * fmaxf(gv, 0.f));
        }
      }
    }
  }
}

// ---------------- MFMA sparse attention (layers 0..L-2): 4 waves/block, 1 head/wave
// (R10 version — best measured)
__global__ __launch_bounds__(256) void attn_mfma_kernel(const u16* __restrict__ Q,
                                                        const u16* __restrict__ K,
                                                        const u16* __restrict__ V,
                                                        const float* __restrict__ maskF,
                                                        u16* __restrict__ O) {
  __shared__ u16 lds_all[4][8064];
  const int wave = threadIdx.x >> 6, lane = threadIdx.x & 63;
  const int b = blockIdx.x >> 1;
  const int h = (blockIdx.x & 1) * 4 + wave;
  u16* VT = &lds_all[wave][0];
  u16* P  = &lds_all[wave][64 * 72];
  const size_t hbase = (size_t)b * (Sq * Dq) + (size_t)h * 64;
  const int r16 = lane & 15, quad = lane >> 4;

  const uint4 z4 = {0u, 0u, 0u, 0u};
  for (int t = lane; t < 576; t += 64) ((uint4*)VT)[t] = z4;
  for (int t = lane; t < 432; t += 64) ((uint4*)P)[t]  = z4;
  for (int t = lane; t < 264; t += 64) {
    const int j = t >> 3, ck = t & 7;
    const uint4 src = *(const uint4*)(V + hbase + (size_t)j * Dq + ck * 8);
    const u16* sp = (const u16*)&src;
#pragma unroll
    for (int e = 0; e < 8; e++) VT[(ck * 8 + e) * 72 + j] = sp[e];
  }
  __syncthreads();

  bf16x8 qf[3][2], kf[3][2];
#pragma unroll
  for (int m = 0; m < 3; m++) {
    const int rl = (m * 16 + r16 < Sq) ? (m * 16 + r16) : (Sq - 1);
#pragma unroll
    for (int kk = 0; kk < 2; kk++) {
      qf[m][kk] = *(const bf16x8*)(Q + hbase + (size_t)rl * Dq + kk * 32 + quad * 8);
      kf[m][kk] = *(const bf16x8*)(K + hbase + (size_t)rl * Dq + kk * 32 + quad * 8);
    }
  }
  f32x4 acc[3][3];
#pragma unroll
  for (int m = 0; m < 3; m++)
#pragma unroll
    for (int n = 0; n < 3; n++) acc[m][n] = (f32x4){0.f, 0.f, 0.f, 0.f};
#pragma unroll
  for (int kk = 0; kk < 2; kk++)
#pragma unroll
    for (int m = 0; m < 3; m++)
#pragma unroll
      for (int n = 0; n < 3; n++)
        acc[m][n] = __builtin_amdgcn_mfma_f32_16x16x32_bf16(qf[m][kk], kf[n][kk], acc[m][n], 0, 0, 0);

  float linv[3][4];
#pragma unroll
  for (int m = 0; m < 3; m++) {
    float v[3][4];
#pragma unroll
    for (int n = 0; n < 3; n++) {
      const int c = n * 16 + r16;
#pragma unroll
      for (int r = 0; r < 4; r++) {
        const int R = m * 16 + quad * 4 + r;
        v[n][r] = acc[m][n][r] * 0.125f + maskF[R * 48 + c];
      }
    }
    float mr[4], sum[4];
#pragma unroll
    for (int r = 0; r < 4; r++) {
      mr[r] = fmaxf(fmaxf(v[0][r], v[1][r]), v[2][r]);
#pragma unroll
      for (int off = 8; off > 0; off >>= 1) mr[r] = fmaxf(mr[r], __shfl_xor(mr[r], off));
      sum[r] = 0.f;
    }
#pragma unroll
    for (int n = 0; n < 3; n++)
#pragma unroll
      for (int r = 0; r < 4; r++) { v[n][r] = __expf(v[n][r] - mr[r]); sum[r] += v[n][r]; }
#pragma unroll
    for (int r = 0; r < 4; r++) {
#pragma unroll
      for (int off = 8; off > 0; off >>= 1) sum[r] += __shfl_xor(sum[r], off);
      linv[m][r] = 1.0f / sum[r];
    }
#pragma unroll
    for (int n = 0; n < 3; n++)
#pragma unroll
      for (int r = 0; r < 4; r++)
        P[(m * 16 + quad * 4 + r) * 72 + n * 16 + r16] = f2bf(v[n][r]);
  }
  __syncthreads();

  bf16x8 pa[3][2], vb[4][2];
#pragma unroll
  for (int m = 0; m < 3; m++)
#pragma unroll
    for (int kk = 0; kk < 2; kk++)
      pa[m][kk] = *(const bf16x8*)(P + (m * 16 + r16) * 72 + kk * 32 + quad * 8);
#pragma unroll
  for (int n = 0; n < 4; n++)
#pragma unroll
    for (int kk = 0; kk < 2; kk++)
      vb[n][kk] = *(const bf16x8*)(VT + (n * 16 + r16) * 72 + kk * 32 + quad * 8);
  f32x4 o[3][4];
#pragma unroll
  for (int m = 0; m < 3; m++)
#pragma unroll
    for (int n = 0; n < 4; n++) o[m][n] = (f32x4){0.f, 0.f, 0.f, 0.f};
#pragma unroll
  for (int kk = 0; kk < 2; kk++)
#pragma unroll
    for (int m = 0; m < 3; m++)
#pragma unroll
      for (int n = 0; n < 4; n++)
        o[m][n] = __builtin_amdgcn_mfma_f32_16x16x32_bf16(pa[m][kk], vb[n][kk], o[m][n], 0, 0, 0);

#pragma unroll
  for (int m = 0; m < 3; m++)
#pragma unroll
    for (int r = 0; r < 4; r++) {
      const int i = m * 16 + quad * 4 + r;
      if (i < Sq) {
#pragma unroll
        for (int n = 0; n < 4; n++)
          O[hbase + (size_t)i * Dq + n * 16 + r16] = f2bf(o[m][n][r] * linv[m][r]);
      }
    }
}

// ---------------- last-layer CLS-only attention: one wave per (b,h).
__global__ __launch_bounds__(256) void attn_cls_kernel(const u16* __restrict__ Qc,
                                                       const u16* __restrict__ Kf,
                                                       const u16* __restrict__ Vf,
                                                       u16* __restrict__ Oc) {
  __shared__ u16 lds[4][4432];
  __shared__ float psh[4][40];
  const int wave = threadIdx.x >> 6, lane = threadIdx.x & 63;
  const int b = blockIdx.x >> 1;
  const int h = (blockIdx.x & 1) * 4 + wave;
  u16* Kl = &lds[wave][0];
  u16* Vl = &lds[wave][2178];
  u16* ql = &lds[wave][4360];
  const size_t hbase = (size_t)b * (Sq * Dq) + (size_t)h * 64;

  for (int t = lane; t < 528; t += 64) {
    const int mtx = (t >= 264) ? 1 : 0;
    const int e = t - mtx * 264;
    const int j = e >> 3, ck = e & 7;
    const uint4 v = *(const uint4*)((mtx ? Vf : Kf) + hbase + (size_t)j * Dq + ck * 8);
    u16* dst = (mtx ? Vl : Kl) + j * 66 + ck * 8;
    const u16* sp = (const u16*)&v;
#pragma unroll
    for (int e2 = 0; e2 < 8; e2++) dst[e2] = sp[e2];
  }
  if (lane < 8)
    *(uint4*)(ql + lane * 8) = *(const uint4*)(Qc + (size_t)b * Dq + h * 64 + lane * 8);
  __syncthreads();

  float p;
  if (lane < Sq) {
    float s = 0.f;
#pragma unroll 16
    for (int d = 0; d < 64; d++) s += bf2f(ql[d]) * bf2f(Kl[lane * 66 + d]);
    p = s * 0.125f;
  } else p = -3e38f;
  float mx = p;
#pragma unroll
  for (int off = 32; off > 0; off >>= 1) mx = fmaxf(mx, __shfl_xor(mx, off));
  float e = (lane < Sq) ? __expf(p - mx) : 0.f;
  float sum = e;
#pragma unroll
  for (int off = 32; off > 0; off >>= 1) sum += __shfl_xor(sum, off);
  if (lane < Sq) psh[wave][lane] = e / sum;
  __syncthreads();

  float o = 0.f;
#pragma unroll
  for (int j = 0; j < Sq; j++) o += psh[wave][j] * bf2f(Vl[j * 66 + lane]);
  Oc[(size_t)b * Dq + h * 64 + lane] = f2bf(o);
}

// ---------------- head: LN(CLS) -> relu -> dot Wh + bh, one wave per sample
__global__ __launch_bounds__(256) void head_kernel(const float* __restrict__ X,
                                                   const float* __restrict__ hw, const float* __restrict__ hb,
                                                   const float* __restrict__ Wh, const float* __restrict__ bh,
                                                   float* __restrict__ out) {
  const int wave = threadIdx.x >> 6, lane = threadIdx.x & 63;
  const int b = blockIdx.x * 4 + wave;
  const float* xr = X + ((size_t)b * Sq + (Sq - 1)) * Dq + lane * 8;
  const float4 a  = *(const float4*)xr;
  const float4 bb = *(const float4*)(xr + 4);
  const float xv[8] = {a.x, a.y, a.z, a.w, bb.x, bb.y, bb.z, bb.w};
  float s = 0.f, ss = 0.f;
#pragma unroll
  for (int i = 0; i < 8; i++) { s += xv[i]; ss += xv[i] * xv[i]; }
#pragma unroll
  for (int off = 32; off > 0; off >>= 1) { s += __shfl_xor(s, off); ss += __shfl_xor(ss, off); }
  const float mean = s * (1.0f / Dq);
  const float rstd = rsqrtf(ss * (1.0f / Dq) - mean * mean + 1e-5f);
  float part = 0.f;
#pragma unroll
  for (int i = 0; i < 8; i++) {
    const float c = (xv[i] - mean) * rstd * hw[lane * 8 + i] + hb[lane * 8 + i];
    part += fmaxf(c, 0.f) * Wh[lane * 8 + i];
  }
#pragma unroll
  for (int off = 32; off > 0; off >>= 1) part += __shfl_xor(part, off);
  if (lane == 0) out[b] = part + bh[0];
}

extern "C" void kernel_launch(void* const* d_in, const int* in_sizes, int n_in,
                              void* d_out, int out_size, void* d_ws, size_t ws_size,
                              hipStream_t stream) {
  (void)in_sizes; (void)n_in; (void)out_size;
  const float* x_num   = (const float*)d_in[0];
  const int*   x_cat   = (const int*)d_in[1];
  const float* w_num   = (const float*)d_in[2];
  const float* b_num   = (const float*)d_in[3];
  const float* emb_cat = (const float*)d_in[4];
  const float* b_cat   = (const float*)d_in[5];
  const float* cls     = (const float*)d_in[6];
  const float* ln1_w   = (const float*)d_in[7];
  const float* ln1_b   = (const float*)d_in[8];
  const float* Wq      = (const float*)d_in[9];
  const float* bq      = (const float*)d_in[10];
  const float* Wk      = (const float*)d_in[11];
  const float* bk      = (const float*)d_in[12];
  const float* Wv      = (const float*)d_in[13];
  const float* bv      = (const float*)d_in[14];
  const float* Wo      = (const float*)d_in[15];
  const float* bo      = (const float*)d_in[16];
  const float* ln2_w   = (const float*)d_in[17];
  const float* ln2_b   = (const float*)d_in[18];
  const float* Wf1     = (const float*)d_in[19];
  const float* bf1     = (const float*)d_in[20];
  const float* Wf2     = (const float*)d_in[21];
  const float* bf2     = (const float*)d_in[22];
  const void*  mask    = d_in[23];
  const float* hln_w   = (const float*)d_in[25];
  const float* hln_b   = (const float*)d_in[26];
  const float* Wh      = (const float*)d_in[27];
  const float* bhp     = (const float*)d_in[28];
  float* out = (float*)d_out;

  const size_t WBYTES = 15728640ULL;
  const size_t MFB    = 27648ULL;
  int Bc = Bq;
  while (Bc > 128) {
    const size_t need = WBYTES + MFB + (size_t)Bc * Sq * 6144ULL;
    if (need <= ws_size) break;
    Bc >>= 1;
  }
  const size_t Mc = (size_t)Bc * Sq;

  char* ws = (char*)d_ws;
  u16* Wbase = (u16*)ws;
  float* maskF = (float*)(ws + WBYTES);
  float* X   = (float*)(ws + WBYTES + MFB);
  u16* Hb    = (u16*)((char*)X + Mc * 2048);
  u16* Qb    = (u16*)((char*)Hb + Mc * 1024);
  u16* Kb    = Qb + Mc * 512;
  u16* Vb    = Kb + Mc * 512;
  u16* AGb   = Qb;

  u16* WqkvT = Wbase;
  u16* WoT   = WqkvT + 2359296;
  u16* Wf1T  = WoT   + 786432;
  u16* Wf2T  = Wf1T  + 3145728;

  wconv_all_kernel<<<dim3(2560, 3), 256, 0, stream>>>(Wq, Wk, Wv, Wo, Wf1, Wf2,
                                                      WqkvT, WoT, Wf1T, Wf2T);
  maskf_kernel<<<Lq, 256, 0, stream>>>(mask, maskF);

  const int mb  = (int)(Mc / 128);
  const int mbC = Bc / 128;

  for (int c0 = 0; c0 < Bq; c0 += Bc) {
    tok_ln_kernel<<<(int)(Mc / 4), 256, 0, stream>>>(x_num, x_cat, w_num, b_num, emb_cat, b_cat, cls,
                                                     ln1_w, ln1_b, X, Hb, c0);

    for (int l = 0; l < Lq; l++) {
      if (l < Lq - 1) {
        gemm_kernel<3><<<dim3(12, mb, 1), 256, 0, stream>>>(Hb,
            WqkvT + l * 786432, nullptr, nullptr,
            bq + l * 512, bk + l * 512, bv + l * 512,
            Qb, nullptr, nullptr, Mc * 512, 512, 1, 0, 1, 0, 0);
        attn_mfma_kernel<<<Bc * 2, 256, 0, stream>>>(Qb, Kb, Vb, maskF + l * 2304, Hb);
        gemm_kernel<1><<<dim3(4, mb, 1), 256, 0, stream>>>(Hb,
            WoT + l * 262144, WoT + l * 262144, WoT + l * 262144,
            bo + l * 512, bo + l * 512, bo + l * 512,
            X, X, X, 0, 512, 1, 0, 1, 0, 0);
        ln_kernel<<<(int)(Mc / 4), 256, 0, stream>>>(X, ln2_w + l * 512, ln2_b + l * 512, Hb, 1, 0);
        gemm_kernel<2><<<dim3(16, mb, 1), 256, 0, stream>>>(Hb,
            Wf1T + l * 1048576, Wf1T + l * 1048576, Wf1T + l * 1048576,
            bf1 + l * 2048, bf1 + l * 2048, bf1 + l * 2048,
            AGb, AGb, AGb, 0, 512, 1, 0, 1, 0, 0);
        gemm_kernel<1><<<dim3(4, mb, 1), 256, 0, stream>>>(AGb,
            Wf2T + l * 524288, Wf2T + l * 524288, Wf2T + l * 524288,
            bf2 + l * 512, bf2 + l * 512, bf2 + l * 512,
            X, X, X, 0, 1024, 1, 0, 1, 0, 0);
        ln_kernel<<<(int)(Mc / 4), 256, 0, stream>>>(X, ln1_w + (l + 1) * 512, ln1_b + (l + 1) * 512, Hb, 1, 0);
      } else {
        gemm_kernel<3><<<dim3(8, mb, 1), 256, 0, stream>>>(Hb,
            WqkvT + l * 786432, nullptr, nullptr,
            bq + l * 512, bk + l * 512, bv + l * 512,
            Qb, nullptr, nullptr, Mc * 512, 512, 1, 0, 1, 0, 4);
        gemm_kernel<3><<<dim3(4, mbC, 1), 256, 0, stream>>>(Hb,
            WqkvT + l * 786432, nullptr, nullptr,
            bq + l * 512, bk + l * 512, bv + l * 512,
            Qb, nullptr, nullptr, Mc * 512, 512, Sq, Sq - 1, 1, 0, 0);
        attn_cls_kernel<<<Bc * 2, 256, 0, stream>>>(Qb, Kb, Vb, Hb);
        gemm_kernel<1><<<dim3(4, mbC, 1), 256, 0, stream>>>(Hb,
            WoT + l * 262144, WoT + l * 262144, WoT + l * 262144,
            bo + l * 512, bo + l * 512, bo + l * 512,
            X, X, X, 0, 512, 1, 0, Sq, Sq - 1, 0);
        ln_kernel<<<Bc / 4, 256, 0, stream>>>(X, ln2_w + l * 512, ln2_b + l * 512, Kb, Sq, Sq - 1);
        gemm_kernel<2><<<dim3(16, mbC, 1), 256, 0, stream>>>(Kb,
            Wf1T + l * 1048576, Wf1T + l * 1048576, Wf1T + l * 1048576,
            bf1 + l * 2048, bf1 + l * 2048, bf1 + l * 2048,
            AGb, AGb, AGb, 0, 512, 1, 0, 1, 0, 0);
        gemm_kernel<1><<<dim3(4, mbC, 1), 256, 0, stream>>>(AGb,
            Wf2T + l * 524288, Wf2T + l * 524288, Wf2T + l * 524288,
            bf2 + l * 512, bf2 + l * 512, bf2 + l * 512,
            X, X, X, 0, 1024, 1, 0, Sq, Sq - 1, 0);
      }
    }
    head_kernel<<<Bc / 4, 256, 0, stream>>>(X, hln_w, hln_b, Wh, bhp, out + c0);
  }
}